// Round 1
// baseline (1268.182 us; speedup 1.0000x reference)
//
#include <hip/hip_runtime.h>
#include <cstdint>

// ODE Euler scan: B=1024, T=4096, S=8, E=8, H=32.
// One wave (64 lanes) per batch element; 1024 blocks x 64 threads = 1 wave/SIMD.
// lane j=l&31 owns hidden unit j (both halves compute matvec1+tanh redundantly),
// halves own s-quads (half0: s0-3, half1: s4-7) for matvec2.
// DPP row_shr reduction + ds_bpermute broadcast. Head done in 64-step bursts.

#if __has_builtin(__builtin_amdgcn_exp2f)
#define EXP2F(v) __builtin_amdgcn_exp2f(v)
#else
#define EXP2F(v) __exp2f(v)
#endif
#if __has_builtin(__builtin_amdgcn_rcpf)
#define RCPF(v) __builtin_amdgcn_rcpf(v)
#else
#define RCPF(v) (1.0f / (v))
#endif

template <int CTRL, int RM>
__device__ __forceinline__ float dpp_add(float x) {
  // old=0 so disabled rows / out-of-range sources contribute 0 either way.
  int sh = __builtin_amdgcn_update_dpp(0, __float_as_int(x), CTRL, RM, 0xF, true);
  return x + __int_as_float(sh);
}

// Sum over each 32-lane group; result valid in lane 31 (group 0) / lane 63 (group 1).
__device__ __forceinline__ float reduce32(float x) {
  x = dpp_add<0x111, 0xF>(x);  // row_shr:1
  x = dpp_add<0x112, 0xF>(x);  // row_shr:2
  x = dpp_add<0x114, 0xF>(x);  // row_shr:4
  x = dpp_add<0x118, 0xF>(x);  // row_shr:8  -> lane15/31/47/63 hold row sums
  x = dpp_add<0x142, 0xA>(x);  // row_bcast15 into rows 1,3 -> lanes 31/63 hold 32-sums
  return x;
}

__device__ __forceinline__ float bperm(int byteaddr, float v) {
  return __int_as_float(__builtin_amdgcn_ds_bpermute(byteaddr, __float_as_int(v)));
}

__global__ __launch_bounds__(64, 1) void ode_scan_kernel(
    const float* __restrict__ x, const float* __restrict__ t,
    const float* __restrict__ y0, const float* __restrict__ Wr1,
    const float* __restrict__ br1, const float* __restrict__ Wr2,
    const float* __restrict__ br2, const float* __restrict__ W1,
    const float* __restrict__ b1, const float* __restrict__ W2,
    const float* __restrict__ b2, float* __restrict__ out) {
  constexpr int T = 4096;

  __shared__ __align__(16) float t_lds[4096];     // t, then dt in-place
  __shared__ __align__(16) float xbuf[2 * 64 * 8]; // double-buffered 64-step x chunks
  __shared__ __align__(16) float ybuf[64 * 12];    // 64 y-slots, rows padded to 12 floats
  __shared__ float hw[112];                        // head weights: W1(80) b1(10) W2(20) b2(2)

  const int l = threadIdx.x;
  const int b = blockIdx.x;
  const int j = l & 31;
  const int half = l >> 5;
  const int sO = half * 4;        // own s-quad base
  const int sX = 4 - half * 4;    // other s-quad base

  // ---- stage t into LDS (coalesced float4) ----
  const float4* t4 = (const float4*)t;
  #pragma unroll
  for (int it = 0; it < 16; ++it) {
    float4 v = t4[it * 64 + l];
    *(float4*)&t_lds[(it * 64 + l) * 4] = v;
  }
  // ---- dt in place: t_lds[i] = t[i+1]-t[i]. Single wave => DS in-order; iteration
  // k's reads ([64k,64k+64]) complete before iteration k+1's writes ([64k+64,...)).
  for (int it = 0; it < 64; ++it) {
    int i = it * 64 + l;
    float a = t_lds[i];
    float c = (i < T - 1) ? t_lds[i + 1] : 0.0f;
    t_lds[i] = c - a;  // i==4095 slot becomes garbage; never consumed as dt
  }

  // ---- head weights into LDS ----
  for (int v = l; v < 112; v += 64) {
    float w;
    if (v < 80) w = W1[v];
    else if (v < 90) w = b1[v - 80];
    else if (v < 110) w = W2[v - 90];
    else w = b2[v - 110];
    hw[v] = w;
  }

  // ---- per-lane recurrence weights ----
  float wyO[4], wyX[4], weq[8], w2q[4], br2q[4];
  #pragma unroll
  for (int q = 0; q < 4; ++q) {
    wyO[q] = Wr1[(sO + q) * 32 + j];
    wyX[q] = Wr1[(sX + q) * 32 + j];
    w2q[q] = Wr2[j * 8 + sO + q];
    br2q[q] = (j == 0) ? br2[sO + q] : 0.0f;  // fold br2 once per s via lane j==0
  }
  #pragma unroll
  for (int r = 0; r < 8; ++r) weq[r] = Wr1[(8 + r) * 32 + j];
  const float br1j = br1[j];

  // ---- y state (own quad + other-half quad, all lanes) ----
  float yO[4], yX[4];
  #pragma unroll
  for (int q = 0; q < 4; ++q) {
    yO[q] = y0[b * 8 + sO + q];
    yX[q] = y0[b * 8 + sX + q];
  }

  // ---- stage x chunk 0 ----
  const float* xbase = x + (size_t)b * (T * 8);
  {
    float4 a0 = *(const float4*)&xbase[l * 8 + 0];
    float4 a1 = *(const float4*)&xbase[l * 8 + 4];
    *(float4*)&xbuf[l * 8 + 0] = a0;
    *(float4*)&xbuf[l * 8 + 4] = a1;
  }

  // write y0 into slot 0 (lanes 0 and 32 each write their quad)
  if (j == 0) *(float4*)&ybuf[0 * 12 + sO] = make_float4(yO[0], yO[1], yO[2], yO[3]);

  // bpermute source byte-addresses (constant per lane)
  const int aO = (half ? 63 : 31) * 4;
  const int aX = (half ? 31 : 63) * 4;

  float2* out2 = (float2*)out + (size_t)b * T;

  // prefetched e/dt for step i=0
  float4 e0 = *(float4*)&xbuf[0];
  float4 e1 = *(float4*)&xbuf[4];
  float dtc = t_lds[0];

  #pragma unroll 1
  for (int c = 0; c < 64; ++c) {
    // issue global loads for chunk c+1 (consumed via ds_write mid-chunk)
    float4 g0 = make_float4(0.f, 0.f, 0.f, 0.f), g1 = g0;
    if (c < 63) {
      g0 = *(const float4*)&xbase[(c + 1) * 512 + l * 8 + 0];
      g1 = *(const float4*)&xbase[(c + 1) * 512 + l * 8 + 4];
    }

    auto step = [&](int k) {
      const int inext = c * 64 + k;  // current step index i = inext-1
      // prefetch next step's e/dt (hides LDS latency)
      float4 ne0 = *(float4*)&xbuf[(inext & 127) * 8 + 0];
      float4 ne1 = *(float4*)&xbuf[(inext & 127) * 8 + 4];
      float ndt = t_lds[inext];

      // edot = br1[j] + sum_r e[r]*Wr1[8+r][j]   (off critical chain)
      float ed = fmaf(e0.x, weq[0], br1j);
      ed = fmaf(e0.y, weq[1], ed);
      ed = fmaf(e0.z, weq[2], ed);
      ed = fmaf(e0.w, weq[3], ed);
      float ed2 = e1.x * weq[4];
      ed2 = fmaf(e1.y, weq[5], ed2);
      ed2 = fmaf(e1.z, weq[6], ed2);
      ed2 = fmaf(e1.w, weq[7], ed2);
      // ydot = sum_s y[s]*Wr1[s][j]  (two 4-chains)
      float yd = yO[0] * wyO[0];
      yd = fmaf(yO[1], wyO[1], yd);
      yd = fmaf(yO[2], wyO[2], yd);
      yd = fmaf(yO[3], wyO[3], yd);
      float yd2 = yX[0] * wyX[0];
      yd2 = fmaf(yX[1], wyX[1], yd2);
      yd2 = fmaf(yX[2], wyX[2], yd2);
      yd2 = fmaf(yX[3], wyX[3], yd2);
      float acc = (ed + ed2) + (yd + yd2);

      // h_j = tanh(acc) = 1 - 2/(exp2(acc*2*log2e)+1)
      float u = EXP2F(acc * 2.885390081777927f);
      float h = fmaf(-2.0f, RCPF(u + 1.0f), 1.0f);

      // p_q = h*Wr2[j][sO+q] (+br2 on lane j==0), reduce over the 32 j's
      float rO[4];
      #pragma unroll
      for (int q = 0; q < 4; ++q) rO[q] = reduce32(fmaf(h, w2q[q], br2q[q]));

      // broadcast sums from lanes 31/63 and Euler-update both y quads
      #pragma unroll
      for (int q = 0; q < 4; ++q) {
        yO[q] = fmaf(dtc, bperm(aO, rO[q]), yO[q]);
        yX[q] = fmaf(dtc, bperm(aX, rO[q]), yX[q]);
      }

      // record y_{tau} (tau = inext) into slot k
      if (j == 0) *(float4*)&ybuf[k * 12 + sO] = make_float4(yO[0], yO[1], yO[2], yO[3]);

      e0 = ne0; e1 = ne1; dtc = ndt;
    };

    #pragma unroll 2
    for (int k = (c ? 0 : 1); k < 8; ++k) step(k);

    // stage chunk c+1 into the other LDS buffer (vmcnt mostly drained by now;
    // that buffer's last reader was chunk c-1's final prefetch)
    if (c < 63) {
      *(float4*)&xbuf[((c + 1) & 1) * 512 + l * 8 + 0] = g0;
      *(float4*)&xbuf[((c + 1) & 1) * 512 + l * 8 + 4] = g1;
    }

    #pragma unroll 2
    for (int k = 8; k < 64; ++k) step(k);

    // ---- head burst: lane k' = l handles tau = c*64 + l ----
    {
      float4 ya = *(float4*)&ybuf[l * 12 + 0];
      float4 yb = *(float4*)&ybuf[l * 12 + 4];
      float ys[8] = {ya.x, ya.y, ya.z, ya.w, yb.x, yb.y, yb.z, yb.w};
      float o0 = hw[110], o1 = hw[111];
      #pragma unroll
      for (int m = 0; m < 10; ++m) {
        float hh = hw[80 + m];
        #pragma unroll
        for (int s = 0; s < 8; ++s) hh = fmaf(ys[s], hw[s * 10 + m], hh);
        hh = fmaxf(hh, 0.0f);
        o0 = fmaf(hh, hw[90 + m * 2 + 0], o0);
        o1 = fmaf(hh, hw[90 + m * 2 + 1], o1);
      }
      out2[c * 64 + l] = make_float2(o0, o1);
    }
  }
}

extern "C" void kernel_launch(void* const* d_in, const int* in_sizes, int n_in,
                              void* d_out, int out_size, void* d_ws, size_t ws_size,
                              hipStream_t stream) {
  const float* x   = (const float*)d_in[0];
  const float* t   = (const float*)d_in[1];
  const float* y0  = (const float*)d_in[2];
  const float* Wr1 = (const float*)d_in[3];
  const float* br1 = (const float*)d_in[4];
  const float* Wr2 = (const float*)d_in[5];
  const float* br2 = (const float*)d_in[6];
  const float* W1  = (const float*)d_in[7];
  const float* b1  = (const float*)d_in[8];
  const float* W2  = (const float*)d_in[9];
  const float* b2  = (const float*)d_in[10];
  (void)in_sizes; (void)n_in; (void)out_size; (void)d_ws; (void)ws_size;

  ode_scan_kernel<<<dim3(1024), dim3(64), 0, stream>>>(x, t, y0, Wr1, br1, Wr2,
                                                       br2, W1, b1, W2, b2,
                                                       (float*)d_out);
}